// Round 21
// baseline (99.622 us; speedup 1.0000x reference)
//
#include <hip/hip_runtime.h>

// ---------------------------------------------------------------------------
// MultiHeadAttention (B=2, T=2048, D=1024, NH=16, hd=64) with ALiBi + causal.
// r20: r19 (best: 98.7us) + T1 XCD-aware block swizzle on qkv_gemm: 1D grid,
// each presumed-XCD (bid&7) owns 4 bm panels x all (bn,z) -> x fetched once
// globally (was once per XCD), W once per XCD. Bijective remap; correctness
// independent of actual XCD mapping. attn/out/cvt byte-identical to r19.
// ---------------------------------------------------------------------------

using f32x4  = __attribute__((ext_vector_type(4))) float;
using bf16x8 = __attribute__((ext_vector_type(8))) short;
typedef unsigned short u16;
using u16x4 = __attribute__((ext_vector_type(4))) u16;
using u32x4 = __attribute__((ext_vector_type(4))) unsigned int;

#define T_SEQ  2048
#define NHEAD  16
#define HDIM   64
#define DMODEL 1024
#define MROWS  4096   // B*T

#define LOG2E 1.4426950408889634f

__device__ __forceinline__ u16 f2bf(float f) {
  union { float f; unsigned u; } v; v.f = f;
  return (u16)((v.u + 0x7fffu + ((v.u >> 16) & 1u)) >> 16);  // RNE
}

__device__ __forceinline__ unsigned cvt_pk_bf16(float lo, float hi) {
  unsigned r;
  asm("v_cvt_pk_bf16_f32 %0, %1, %2" : "=v"(r) : "v"(lo), "v"(hi));
  return r;
}

__device__ __forceinline__ void gl_lds16(const u16* g, u16* l) {
  __builtin_amdgcn_global_load_lds(
      (const __attribute__((address_space(1))) unsigned int*)g,
      (__attribute__((address_space(3))) unsigned int*)l, 16, 0, 0);
}

// ---------------------------------------------------------------------------
// merged fp32->bf16 convert: y<4 -> x quarters, y=4..7 -> Wq/Wk/Wv/Wp
__global__ __launch_bounds__(256) void cvt_all(
    const float* __restrict__ x,
    const float* __restrict__ wq, const float* __restrict__ wk,
    const float* __restrict__ wv, const float* __restrict__ wp,
    u16* __restrict__ dst) {
  const int y = blockIdx.y;
  const float* src;
  if (y < 4)       src = x + (size_t)y * 1048576;
  else if (y == 4) src = wq;
  else if (y == 5) src = wk;
  else if (y == 6) src = wv;
  else             src = wp;
  u16* d = dst + (size_t)y * 1048576;
  int i = (blockIdx.x * 256 + threadIdx.x) * 4;
  const float4 v = *reinterpret_cast<const float4*>(src + i);
  u16x4 o;
  o.x = f2bf(v.x); o.y = f2bf(v.y); o.z = f2bf(v.z); o.w = f2bf(v.w);
  *reinterpret_cast<u16x4*>(d + i) = o;
}

// ---------------------------------------------------------------------------
// Fused QKV projection, r13 structure + permuted V^T epilogue + T1 swizzle:
// 1D grid of 768; bid&7 = presumed XCD owns bm in {4*xcd..4*xcd+3}.
__global__ __launch_bounds__(256, 3) void qkv_gemm(
    const u16* __restrict__ xb,
    const u16* __restrict__ wq, const u16* __restrict__ wk, const u16* __restrict__ wv,
    const float* __restrict__ bq, const float* __restrict__ bk, const float* __restrict__ bv,
    u16* __restrict__ q_ws, u16* __restrict__ k_ws, u16* __restrict__ vt_ws)
{
  const int K = DMODEL;
  // XCD-aware decode (bijective): bid -> (bm, bn, z)
  const int bid = blockIdx.x;          // 0..767
  const int xcd = bid & 7;
  const int idx = bid >> 3;            // 0..95
  const int bm  = xcd * 4 + (idx & 3); // 0..31 (4 A-panels per XCD)
  const int rest = idx >> 2;           // 0..23
  const int bn  = rest & 7;            // 0..7
  const int z   = rest >> 3;           // 0..2
  const u16*   W    = (z == 0) ? wq : (z == 1) ? wk : wv;
  const float* bias = (z == 0) ? bq : (z == 1) ? bk : bv;
  const int tid = threadIdx.x;
  const int w = tid >> 6, lane = tid & 63, g = lane >> 4, c = lane & 15;
  const int wm = w >> 1, wn = w & 1;

  __shared__ u16 SM[2][2][128][32];   // [buf][A=0/B=1], 32 KB

  f32x4 zero4 = {0.f, 0.f, 0.f, 0.f};
  f32x4 acc[4][4];
#pragma unroll
  for (int m = 0; m < 4; ++m)
#pragma unroll
    for (int n = 0; n < 4; ++n) acc[m][n] = zero4;

  int rr[2], cswz[2];
#pragma unroll
  for (int jj = 0; jj < 2; ++jj) {
    int chunk = tid + 256 * jj;
    rr[jj] = chunk >> 2;
    cswz[jj] = ((chunk & 3) ^ (rr[jj] & 3)) * 8;
  }
  const int fsw = (g ^ (c & 3)) * 8;

#pragma unroll
  for (int jj = 0; jj < 2; ++jj) {
    int chunk = tid + 256 * jj;
    gl_lds16(xb + (size_t)(bm * 128 + rr[jj]) * K + cswz[jj],
             &SM[0][0][0][0] + chunk * 8);
    gl_lds16(W + (size_t)(bn * 128 + rr[jj]) * K + cswz[jj],
             &SM[0][1][0][0] + chunk * 8);
  }
  __syncthreads();

  for (int t = 0; t < 32; ++t) {
    const int buf = t & 1;
    if (t < 31) {
      const int k0 = (t + 1) * 32;
#pragma unroll
      for (int jj = 0; jj < 2; ++jj) {
        int chunk = tid + 256 * jj;
        gl_lds16(xb + (size_t)(bm * 128 + rr[jj]) * K + k0 + cswz[jj],
                 &SM[buf ^ 1][0][0][0] + chunk * 8);
        gl_lds16(W + (size_t)(bn * 128 + rr[jj]) * K + k0 + cswz[jj],
                 &SM[buf ^ 1][1][0][0] + chunk * 8);
      }
    }
    bf16x8 af[4], bfr[4];
#pragma unroll
    for (int m = 0; m < 4; ++m) {
      int row = wm * 64 + m * 16 + c;
      af[m] = *reinterpret_cast<const bf16x8*>(&SM[buf][0][row][fsw]);
    }
#pragma unroll
    for (int n = 0; n < 4; ++n) {
      int row = wn * 64 + n * 16 + c;
      bfr[n] = *reinterpret_cast<const bf16x8*>(&SM[buf][1][row][fsw]);
    }
#pragma unroll
    for (int m = 0; m < 4; ++m)
#pragma unroll
      for (int n = 0; n < 4; ++n)
        acc[m][n] = __builtin_amdgcn_mfma_f32_16x16x32_bf16(af[m], bfr[n], acc[m][n], 0, 0, 0);
    __syncthreads();
  }

  const float rs = 0.1767766953f;          // 1024^-0.25
  const float qs = rs * LOG2E;

  if (z == 2) {
    u16* tr = &SM[0][0][0][0];   // 64 rows x 136 stride (128 t cols)
    const int bb = (bm * 128) >> 11;
    const int t_base = (bm * 128) & (T_SEQ - 1);
#pragma unroll
    for (int hh = 0; hh < 2; ++hh) {
      __syncthreads();
      if (wn == hh) {
#pragma unroll
        for (int n = 0; n < 4; ++n) {
          float bv_ = bias[bn * 128 + wn * 64 + n * 16 + c];
#pragma unroll
          for (int m = 0; m < 4; ++m) {
#pragma unroll
            for (int i = 0; i < 4; ++i) {
              tr[(n * 16 + c) * 136 + wm * 64 + m * 16 + g * 4 + i] =
                  f2bf(acc[m][n][i] + bv_);
            }
          }
        }
      }
      __syncthreads();
      // PERMUTED store: col' = chunk'*8+j holds col = k*16+gg*4+e
#pragma unroll
      for (int rep = 0; rep < 4; ++rep) {
        int idx2 = tid + rep * 256;
        int dr = idx2 >> 4, ch = idx2 & 15;
        int blk = ch >> 3;
        int chp = ch & 7;
        int r0 = blk * 64 + (chp & 1) * 32 + (chp >> 1) * 4;
        union { short4 s[2]; bf16x8 v; } vv;
        vv.s[0] = *reinterpret_cast<const short4*>(&tr[dr * 136 + r0]);
        vv.s[1] = *reinterpret_cast<const short4*>(&tr[dr * 136 + r0 + 16]);
        int d_glob = bn * 128 + hh * 64 + dr;
        int head = d_glob >> 6, dd = d_glob & 63;
        *reinterpret_cast<bf16x8*>(
            vt_ws + (((size_t)(bb * NHEAD + head) * HDIM + dd) * T_SEQ) + t_base + ch * 8) = vv.v;
      }
    }
  } else {
    u16* dst = (z == 0) ? q_ws : k_ws;
    const float sc = (z == 0) ? qs : rs;
#pragma unroll
    for (int m = 0; m < 4; ++m) {
      int mrow_base = bm * 128 + wm * 64 + m * 16 + g * 4;
#pragma unroll
      for (int n = 0; n < 4; ++n) {
        int n_idx = bn * 128 + wn * 64 + n * 16 + c;
        float bv_ = bias[n_idx];
        int head = n_idx >> 6, d = n_idx & 63;
#pragma unroll
        for (int i = 0; i < 4; ++i) {
          int mrow = mrow_base + i;
          int b = mrow >> 11, t = mrow & (T_SEQ - 1);
          dst[((size_t)(b * NHEAD + head) * T_SEQ + t) * HDIM + d] =
              f2bf((acc[m][n][i] + bv_) * sc);
        }
      }
    }
  }
}

// ---------------------------------------------------------------------------
// Flash attention r16 (verbatim): permuted-V b128 PV (reads inline in PV
// loop), fixed-max softmax, hoisted bases, 1024 uniform blocks, XCD decode,
// dbuf K/V.
__global__ __launch_bounds__(128, 2) void attn_fused(
    const u16* __restrict__ Q, const u16* __restrict__ Kk,
    const u16* __restrict__ VT, u16* __restrict__ O)
{
  const int tid = threadIdx.x;
  const int w = tid >> 6;                     // 0..1
  const int lane = tid & 63;
  const int g = lane >> 4, c = lane & 15;
  const int c7 = c & 7;
  const int bid = blockIdx.x;                 // 0..1023
  const int inner = bid >> 3;                 // 0..127
  const int bh = (bid & 7) + 8 * (inner & 3); // 0..31 (XCD-resident K/V)
  const int j = inner >> 2;                   // 0..31 (pair index)
  const int h = bh & (NHEAD - 1), b = bh >> 4;
  const float slope2 = exp2f(-0.5f * (float)(h + 1)) * LOG2E;
  const u16* Qp = Q  + (size_t)bh * T_SEQ * HDIM;
  const u16* Kp = Kk + (size_t)bh * T_SEQ * HDIM;
  const u16* Vp = VT + (size_t)bh * HDIM * T_SEQ;

  __shared__ u16 KB[2][64][64];   // 16 KB
  __shared__ u16 VB[2][64][64];   // 16 KB

  const int s_rb = tid >> 3;
  const int cs = ((tid & 7) ^ (s_rb & 7)) * 8;
  const u16* KsB = Kp + (size_t)s_rb * HDIM + cs;     // + kv*64 + sw*1024
  const u16* VsB = Vp + (size_t)s_rb * T_SEQ + cs;    // + kv   + sw*32768
  u16* const kd0 = &KB[0][0][0] + tid * 8;            // + par*4096 + sw*1024
  u16* const vd0 = &VB[0][0][0] + tid * 8;
  const int koffA = c * 64 + ((g ^ c7) * 8);
  const int koffB = c * 64 + (((4 + g) ^ c7) * 8);
  const int voffA = c * 64 + (((2 * g)     ^ c7) * 8);
  const int voffB = c * 64 + (((2 * g + 1) ^ c7) * 8);

  f32x4 zero4 = {0.f, 0.f, 0.f, 0.f};

  for (int pass = 0; pass < 2; ++pass) {
    const int qb = (pass == 0) ? (63 - j) : j;      // 32-row q-tile index
    const int q0 = qb * 32;
    const int qrow = q0 + w * 16;                   // wave fragment
    const int nt = (qb >> 1) + 1;                   // kv tiles (64-wide)

    bf16x8 qf0 = *reinterpret_cast<const bf16x8*>(Qp + (size_t)(qrow + c) * HDIM + g * 8);
    bf16x8 qf1 = *reinterpret_cast<const bf16x8*>(Qp + (size_t)(qrow + c) * HDIM + 32 + g * 8);

    {
      const int kv0 = (nt - 1) * 64;
      const u16* ks = KsB + kv0 * 64;
      const u16* vs = VsB + kv0;
      gl_lds16(ks,         kd0);
      gl_lds16(ks + 1024,  kd0 + 1024);
      gl_lds16(ks + 2048,  kd0 + 2048);
      gl_lds16(ks + 3072,  kd0 + 3072);
      gl_lds16(vs,          vd0);
      gl_lds16(vs + 32768,  vd0 + 1024);
      gl_lds16(vs + 65536,  vd0 + 2048);
      gl_lds16(vs + 98304,  vd0 + 3072);
    }
    __syncthreads();

    f32x4 o[4];
#pragma unroll
    for (int dg = 0; dg < 4; ++dg) o[dg] = zero4;
    float lrun = 0.f;

    for (int t = 0; t < nt; ++t) {
      const int par = t & 1;
      const u16* kb = &KB[0][0][0] + par * 4096;
      const u16* vb = &VB[0][0][0] + par * 4096;

      if (t + 1 < nt) {
        const int kvn = (nt - 2 - t) * 64;
        const u16* ks = KsB + kvn * 64;
        const u16* vs = VsB + kvn;
        u16* kd = kd0 + (par ^ 1) * 4096;
        u16* vd = vd0 + (par ^ 1) * 4096;
        gl_lds16(ks,         kd);
        gl_lds16(ks + 1024,  kd + 1024);
        gl_lds16(ks + 2048,  kd + 2048);
        gl_lds16(ks + 3072,  kd + 3072);
        gl_lds16(vs,          vd);
        gl_lds16(vs + 32768,  vd + 1024);
        gl_lds16(vs + 65536,  vd + 2048);
        gl_lds16(vs + 98304,  vd + 3072);
      }

      const int kv0 = (nt - 1 - t) * 64;

      const u16* kA = kb + koffA;
      const u16* kBp = kb + koffB;
      f32x4 s[4];
#pragma unroll
      for (int jj = 0; jj < 4; ++jj) {
        bf16x8 k0 = *reinterpret_cast<const bf16x8*>(kA + jj * 1024);
        bf16x8 k1 = *reinterpret_cast<const bf16x8*>(kBp + jj * 1024);
        f32x4 z4 = zero4;
        z4 = __builtin_amdgcn_mfma_f32_16x16x32_bf16(k0, qf0, z4, 0, 0, 0);
        z4 = __builtin_amdgcn_mfma_f32_16x16x32_bf16(k1, qf1, z4, 0, 0, 0);
        s[jj] = z4;
      }

      const int kbase = kv0 + 4 * g - (qrow + c);
      float p[16];
      if (t == 0) {
#pragma unroll
        for (int jj = 0; jj < 4; ++jj)
#pragma unroll
          for (int i = 0; i < 4; ++i) {
            int rel = kbase + 16 * jj + i;
            float sv = s[jj][i] + slope2 * (float)rel;
            if (rel > 0) sv = -3.0e38f;
            float e = __builtin_amdgcn_exp2f(sv);
            p[jj * 4 + i] = e;
            lrun += e;
          }
      } else {
        const float bb2 = slope2 * (float)kbase;
#pragma unroll
        for (int jj = 0; jj < 4; ++jj)
#pragma unroll
          for (int i = 0; i < 4; ++i) {
            float e = __builtin_amdgcn_exp2f(
                s[jj][i] + (bb2 + slope2 * (float)(16 * jj + i)));
            p[jj * 4 + i] = e;
            lrun += e;
          }
      }
      union PU { bf16x8 v; u32x4 u; };
      PU P0, P1;
#pragma unroll
      for (int k = 0; k < 4; ++k) {
        P0.u[k] = cvt_pk_bf16(p[2 * k], p[2 * k + 1]);
        P1.u[k] = cvt_pk_bf16(p[8 + 2 * k], p[8 + 2 * k + 1]);
      }

      const u16* vpA = vb + voffA;
      const u16* vpB = vb + voffB;
#pragma unroll
      for (int dg = 0; dg < 4; ++dg) {
        bf16x8 vf0 = *reinterpret_cast<const bf16x8*>(vpA + dg * 1024);
        bf16x8 vf1 = *reinterpret_cast<const bf16x8*>(vpB + dg * 1024);
        o[dg] = __builtin_amdgcn_mfma_f32_16x16x32_bf16(P0.v, vf0, o[dg], 0, 0, 0);
        o[dg] = __builtin_amdgcn_mfma_f32_16x16x32_bf16(P1.v, vf1, o[dg], 0, 0, 0);
      }

      __syncthreads();
    }

    lrun += __shfl_xor(lrun, 16, 64);
    lrun += __shfl_xor(lrun, 32, 64);
    float rl[4];
#pragma unroll
    for (int i = 0; i < 4; ++i) {
      float li = __shfl(lrun, g * 4 + i, 64);
      rl[i] = 1.0f / li;
    }
#pragma unroll
    for (int dg = 0; dg < 4; ++dg) {
#pragma unroll
      for (int i = 0; i < 4; ++i) {
        int qi = qrow + g * 4 + i;
        O[((size_t)b * T_SEQ + qi) * DMODEL + h * HDIM + dg * 16 + c] =
            f2bf(o[dg][i] * rl[i]);
      }
    }
    __syncthreads();
  }
}

// ---------------------------------------------------------------------------
// Output projection, r7 (verbatim): 128x128 tile, BK=64 dbuf 2-phase K-loop.
__global__ __launch_bounds__(256) void out_gemm(
    const u16* __restrict__ ao, const u16* __restrict__ wp,
    const float* __restrict__ bp, float* __restrict__ out)
{
  const int K = DMODEL;
  const int bm = blockIdx.y, bn = blockIdx.x;
  const int tid = threadIdx.x;
  const int w = tid >> 6, lane = tid & 63, g = lane >> 4, c = lane & 15;
  const int wm = w >> 1, wn = w & 1;

  __shared__ u16 SM[2][2][128][64];   // 64 KB

  f32x4 zero4 = {0.f, 0.f, 0.f, 0.f};
  f32x4 acc[4][4];
#pragma unroll
  for (int m = 0; m < 4; ++m)
#pragma unroll
    for (int n = 0; n < 4; ++n) acc[m][n] = zero4;

  int rr[4], cswz[4];
#pragma unroll
  for (int j = 0; j < 4; ++j) {
    int chunk = tid + 256 * j;
    rr[j] = chunk >> 3;
    cswz[j] = ((chunk & 7) ^ (rr[j] & 7)) * 8;
  }

  // prologue: stage k0=0 into buf 0
#pragma unroll
  for (int j = 0; j < 4; ++j) {
    int chunk = tid + 256 * j;
    gl_lds16(ao + (size_t)(bm * 128 + rr[j]) * K + cswz[j],
             &SM[0][0][0][0] + chunk * 8);
    gl_lds16(wp + (size_t)(bn * 128 + rr[j]) * K + cswz[j],
             &SM[0][1][0][0] + chunk * 8);
  }
  __syncthreads();

  for (int t = 0; t < 16; ++t) {
    const int buf = t & 1;
    if (t < 15) {
      const int k0 = (t + 1) * 64;
#pragma unroll
      for (int j = 0; j < 4; ++j) {
        int chunk = tid + 256 * j;
        gl_lds16(ao + (size_t)(bm * 128 + rr[j]) * K + k0 + cswz[j],
                 &SM[buf ^ 1][0][0][0] + chunk * 8);
        gl_lds16(wp + (size_t)(bn * 128 + rr[j]) * K + k0 + cswz[j],
                 &SM[buf ^ 1][1][0][0] + chunk * 8);
      }
    }
#pragma unroll
    for (int kk = 0; kk < 2; ++kk) {
      bf16x8 af[4], bfr[4];
#pragma unroll
      for (int m = 0; m < 4; ++m) {
        int row = wm * 64 + m * 16 + c;
        af[m] = *reinterpret_cast<const bf16x8*>(
            &SM[buf][0][row][(kk * 32 + g * 8) ^ ((row & 7) * 8)]);
      }
#pragma unroll
      for (int n = 0; n < 4; ++n) {
        int row = wn * 64 + n * 16 + c;
        bfr[n] = *reinterpret_cast<const bf16x8*>(
            &SM[buf][1][row][(kk * 32 + g * 8) ^ ((row & 7) * 8)]);
      }
#pragma unroll
      for (int m = 0; m < 4; ++m)
#pragma unroll
        for (int n = 0; n < 4; ++n)
          acc[m][n] = __builtin_amdgcn_mfma_f32_16x16x32_bf16(af[m], bfr[n], acc[m][n], 0, 0, 0);
    }
    __syncthreads();
  }

#pragma unroll
  for (int m = 0; m < 4; ++m) {
    int mrow_base = bm * 128 + wm * 64 + m * 16 + g * 4;
#pragma unroll
    for (int n = 0; n < 4; ++n) {
      int n_idx = bn * 128 + wn * 64 + n * 16 + c;
      float bv_ = bp[n_idx];
#pragma unroll
      for (int i = 0; i < 4; ++i) {
        int mrow = mrow_base + i;
        out[(size_t)mrow * DMODEL + n_idx] = acc[m][n][i] + bv_;
      }
    }
  }
}

// ---------------------------------------------------------------------------
extern "C" void kernel_launch(void* const* d_in, const int* in_sizes, int n_in,
                              void* d_out, int out_size, void* d_ws, size_t ws_size,
                              hipStream_t stream) {
  const float* x  = (const float*)d_in[0];
  const float* Wq = (const float*)d_in[1];
  const float* bq = (const float*)d_in[2];
  const float* Wk = (const float*)d_in[3];
  const float* bk = (const float*)d_in[4];
  const float* Wv = (const float*)d_in[5];
  const float* bv = (const float*)d_in[6];
  const float* Wp = (const float*)d_in[7];
  const float* bp = (const float*)d_in[8];
  float* out = (float*)d_out;

  u16* ws    = (u16*)d_ws;
  u16* xb    = ws;                       // 4,194,304  (x as bf16)
  u16* wqb   = xb   + 4194304;           // 4 x 1,048,576 contiguous
  u16* wkb   = wqb  + 1048576;
  u16* wvb   = wkb  + 1048576;
  u16* wpb   = wvb  + 1048576;
  u16* q_ws  = wpb  + 1048576;           // [B,NH,T,hd] (scaled by rs*log2e)
  u16* k_ws  = q_ws + 4194304;           // [B,NH,T,hd] (scaled by rs)
  u16* vt_ws = k_ws + 4194304;           // [B,NH,hd,T] PERMUTED per 64-t block
  u16* ao    = vt_ws + 4194304;          // [B,T,D] attention output

  cvt_all<<<dim3(1024, 8), 256, 0, stream>>>(x, Wq, Wk, Wv, Wp, ws);

  qkv_gemm<<<768, 256, 0, stream>>>(
      xb, wqb, wkb, wvb, bq, bk, bv, q_ws, k_ws, vt_ws);

  attn_fused<<<1024, 128, 0, stream>>>(q_ws, k_ws, vt_ws, ao);

  out_gemm<<<dim3(DMODEL / 128, MROWS / 128), 256, 0, stream>>>(ao, wpb, bp, out);
}

// Round 22
// 98.427 us; speedup vs baseline: 1.0121x; 1.0121x over previous
//
#include <hip/hip_runtime.h>

// ---------------------------------------------------------------------------
// MultiHeadAttention (B=2, T=2048, D=1024, NH=16, hd=64) with ALiBi + causal.
// r21 (FINAL) = r19 verbatim, the best-known ensemble (98.7us):
//   cvt_all:  merged single-launch fp32->bf16 convert (BW-floor ~8us)
//   qkv_gemm: BK=32 dbuf, 32KB LDS, 3 blocks/CU, permuted-V^T epilogue
//   attn:     1024 uniform triangular-paired blocks (32-row q-tiles),
//             2 waves/block, XCD-local K/V (FETCH 12MB), dbuf staging,
//             swapped-QK register softmax with provably-safe fixed max,
//             permuted-V b128 PV, hoisted loop-invariant addressing
//   out_gemm: 128x128 BK=64 dbuf
// r20's T1-on-qkv reverted (null). Structural rewrites beyond this point
// regressed consistently (r5/r8/r14); plateau accepted.
// ---------------------------------------------------------------------------

using f32x4  = __attribute__((ext_vector_type(4))) float;
using bf16x8 = __attribute__((ext_vector_type(8))) short;
typedef unsigned short u16;
using u16x4 = __attribute__((ext_vector_type(4))) u16;
using u32x4 = __attribute__((ext_vector_type(4))) unsigned int;

#define T_SEQ  2048
#define NHEAD  16
#define HDIM   64
#define DMODEL 1024
#define MROWS  4096   // B*T

#define LOG2E 1.4426950408889634f

__device__ __forceinline__ u16 f2bf(float f) {
  union { float f; unsigned u; } v; v.f = f;
  return (u16)((v.u + 0x7fffu + ((v.u >> 16) & 1u)) >> 16);  // RNE
}

__device__ __forceinline__ unsigned cvt_pk_bf16(float lo, float hi) {
  unsigned r;
  asm("v_cvt_pk_bf16_f32 %0, %1, %2" : "=v"(r) : "v"(lo), "v"(hi));
  return r;
}

__device__ __forceinline__ void gl_lds16(const u16* g, u16* l) {
  __builtin_amdgcn_global_load_lds(
      (const __attribute__((address_space(1))) unsigned int*)g,
      (__attribute__((address_space(3))) unsigned int*)l, 16, 0, 0);
}

// ---------------------------------------------------------------------------
// merged fp32->bf16 convert: y<4 -> x quarters, y=4..7 -> Wq/Wk/Wv/Wp
__global__ __launch_bounds__(256) void cvt_all(
    const float* __restrict__ x,
    const float* __restrict__ wq, const float* __restrict__ wk,
    const float* __restrict__ wv, const float* __restrict__ wp,
    u16* __restrict__ dst) {
  const int y = blockIdx.y;
  const float* src;
  if (y < 4)       src = x + (size_t)y * 1048576;
  else if (y == 4) src = wq;
  else if (y == 5) src = wk;
  else if (y == 6) src = wv;
  else             src = wp;
  u16* d = dst + (size_t)y * 1048576;
  int i = (blockIdx.x * 256 + threadIdx.x) * 4;
  const float4 v = *reinterpret_cast<const float4*>(src + i);
  u16x4 o;
  o.x = f2bf(v.x); o.y = f2bf(v.y); o.z = f2bf(v.z); o.w = f2bf(v.w);
  *reinterpret_cast<u16x4*>(d + i) = o;
}

// ---------------------------------------------------------------------------
// Fused QKV projection, r13 structure; z==2 epilogue writes PERMUTED V^T.
__global__ __launch_bounds__(256, 3) void qkv_gemm(
    const u16* __restrict__ xb,
    const u16* __restrict__ wq, const u16* __restrict__ wk, const u16* __restrict__ wv,
    const float* __restrict__ bq, const float* __restrict__ bk, const float* __restrict__ bv,
    u16* __restrict__ q_ws, u16* __restrict__ k_ws, u16* __restrict__ vt_ws)
{
  const int K = DMODEL;
  const int z = blockIdx.z;
  const u16*   W    = (z == 0) ? wq : (z == 1) ? wk : wv;
  const float* bias = (z == 0) ? bq : (z == 1) ? bk : bv;
  const int bm = blockIdx.y, bn = blockIdx.x;
  const int tid = threadIdx.x;
  const int w = tid >> 6, lane = tid & 63, g = lane >> 4, c = lane & 15;
  const int wm = w >> 1, wn = w & 1;

  __shared__ u16 SM[2][2][128][32];   // [buf][A=0/B=1], 32 KB

  f32x4 zero4 = {0.f, 0.f, 0.f, 0.f};
  f32x4 acc[4][4];
#pragma unroll
  for (int m = 0; m < 4; ++m)
#pragma unroll
    for (int n = 0; n < 4; ++n) acc[m][n] = zero4;

  int rr[2], cswz[2];
#pragma unroll
  for (int jj = 0; jj < 2; ++jj) {
    int chunk = tid + 256 * jj;
    rr[jj] = chunk >> 2;
    cswz[jj] = ((chunk & 3) ^ (rr[jj] & 3)) * 8;
  }
  const int fsw = (g ^ (c & 3)) * 8;

#pragma unroll
  for (int jj = 0; jj < 2; ++jj) {
    int chunk = tid + 256 * jj;
    gl_lds16(xb + (size_t)(bm * 128 + rr[jj]) * K + cswz[jj],
             &SM[0][0][0][0] + chunk * 8);
    gl_lds16(W + (size_t)(bn * 128 + rr[jj]) * K + cswz[jj],
             &SM[0][1][0][0] + chunk * 8);
  }
  __syncthreads();

  for (int t = 0; t < 32; ++t) {
    const int buf = t & 1;
    if (t < 31) {
      const int k0 = (t + 1) * 32;
#pragma unroll
      for (int jj = 0; jj < 2; ++jj) {
        int chunk = tid + 256 * jj;
        gl_lds16(xb + (size_t)(bm * 128 + rr[jj]) * K + k0 + cswz[jj],
                 &SM[buf ^ 1][0][0][0] + chunk * 8);
        gl_lds16(W + (size_t)(bn * 128 + rr[jj]) * K + k0 + cswz[jj],
                 &SM[buf ^ 1][1][0][0] + chunk * 8);
      }
    }
    bf16x8 af[4], bfr[4];
#pragma unroll
    for (int m = 0; m < 4; ++m) {
      int row = wm * 64 + m * 16 + c;
      af[m] = *reinterpret_cast<const bf16x8*>(&SM[buf][0][row][fsw]);
    }
#pragma unroll
    for (int n = 0; n < 4; ++n) {
      int row = wn * 64 + n * 16 + c;
      bfr[n] = *reinterpret_cast<const bf16x8*>(&SM[buf][1][row][fsw]);
    }
#pragma unroll
    for (int m = 0; m < 4; ++m)
#pragma unroll
      for (int n = 0; n < 4; ++n)
        acc[m][n] = __builtin_amdgcn_mfma_f32_16x16x32_bf16(af[m], bfr[n], acc[m][n], 0, 0, 0);
    __syncthreads();
  }

  const float rs = 0.1767766953f;          // 1024^-0.25
  const float qs = rs * LOG2E;

  if (z == 2) {
    u16* tr = &SM[0][0][0][0];   // 64 rows x 136 stride (128 t cols)
    const int bb = (bm * 128) >> 11;
    const int t_base = (bm * 128) & (T_SEQ - 1);
#pragma unroll
    for (int hh = 0; hh < 2; ++hh) {
      __syncthreads();
      if (wn == hh) {
#pragma unroll
        for (int n = 0; n < 4; ++n) {
          float bv_ = bias[bn * 128 + wn * 64 + n * 16 + c];
#pragma unroll
          for (int m = 0; m < 4; ++m) {
#pragma unroll
            for (int i = 0; i < 4; ++i) {
              tr[(n * 16 + c) * 136 + wm * 64 + m * 16 + g * 4 + i] =
                  f2bf(acc[m][n][i] + bv_);
            }
          }
        }
      }
      __syncthreads();
      // PERMUTED store: col' = chunk'*8+j holds col = k*16+gg*4+e
#pragma unroll
      for (int rep = 0; rep < 4; ++rep) {
        int idx = tid + rep * 256;
        int dr = idx >> 4, ch = idx & 15;
        int blk = ch >> 3;
        int chp = ch & 7;
        int r0 = blk * 64 + (chp & 1) * 32 + (chp >> 1) * 4;
        union { short4 s[2]; bf16x8 v; } vv;
        vv.s[0] = *reinterpret_cast<const short4*>(&tr[dr * 136 + r0]);
        vv.s[1] = *reinterpret_cast<const short4*>(&tr[dr * 136 + r0 + 16]);
        int d_glob = bn * 128 + hh * 64 + dr;
        int head = d_glob >> 6, dd = d_glob & 63;
        *reinterpret_cast<bf16x8*>(
            vt_ws + (((size_t)(bb * NHEAD + head) * HDIM + dd) * T_SEQ) + t_base + ch * 8) = vv.v;
      }
    }
  } else {
    u16* dst = (z == 0) ? q_ws : k_ws;
    const float sc = (z == 0) ? qs : rs;
#pragma unroll
    for (int m = 0; m < 4; ++m) {
      int mrow_base = bm * 128 + wm * 64 + m * 16 + g * 4;
#pragma unroll
      for (int n = 0; n < 4; ++n) {
        int n_idx = bn * 128 + wn * 64 + n * 16 + c;
        float bv_ = bias[n_idx];
        int head = n_idx >> 6, d = n_idx & 63;
#pragma unroll
        for (int i = 0; i < 4; ++i) {
          int mrow = mrow_base + i;
          int b = mrow >> 11, t = mrow & (T_SEQ - 1);
          dst[((size_t)(b * NHEAD + head) * T_SEQ + t) * HDIM + d] =
              f2bf((acc[m][n][i] + bv_) * sc);
        }
      }
    }
  }
}

// ---------------------------------------------------------------------------
// Flash attention r16 (verbatim): permuted-V b128 PV (reads inline in PV
// loop), fixed-max softmax, hoisted bases, 1024 uniform blocks, XCD decode,
// dbuf K/V.
__global__ __launch_bounds__(128, 2) void attn_fused(
    const u16* __restrict__ Q, const u16* __restrict__ Kk,
    const u16* __restrict__ VT, u16* __restrict__ O)
{
  const int tid = threadIdx.x;
  const int w = tid >> 6;                     // 0..1
  const int lane = tid & 63;
  const int g = lane >> 4, c = lane & 15;
  const int c7 = c & 7;
  const int bid = blockIdx.x;                 // 0..1023
  const int inner = bid >> 3;                 // 0..127
  const int bh = (bid & 7) + 8 * (inner & 3); // 0..31 (XCD-resident K/V)
  const int j = inner >> 2;                   // 0..31 (pair index)
  const int h = bh & (NHEAD - 1), b = bh >> 4;
  const float slope2 = exp2f(-0.5f * (float)(h + 1)) * LOG2E;
  const u16* Qp = Q  + (size_t)bh * T_SEQ * HDIM;
  const u16* Kp = Kk + (size_t)bh * T_SEQ * HDIM;
  const u16* Vp = VT + (size_t)bh * HDIM * T_SEQ;

  __shared__ u16 KB[2][64][64];   // 16 KB
  __shared__ u16 VB[2][64][64];   // 16 KB

  const int s_rb = tid >> 3;
  const int cs = ((tid & 7) ^ (s_rb & 7)) * 8;
  const u16* KsB = Kp + (size_t)s_rb * HDIM + cs;     // + kv*64 + sw*1024
  const u16* VsB = Vp + (size_t)s_rb * T_SEQ + cs;    // + kv   + sw*32768
  u16* const kd0 = &KB[0][0][0] + tid * 8;            // + par*4096 + sw*1024
  u16* const vd0 = &VB[0][0][0] + tid * 8;
  const int koffA = c * 64 + ((g ^ c7) * 8);
  const int koffB = c * 64 + (((4 + g) ^ c7) * 8);
  const int voffA = c * 64 + (((2 * g)     ^ c7) * 8);
  const int voffB = c * 64 + (((2 * g + 1) ^ c7) * 8);

  f32x4 zero4 = {0.f, 0.f, 0.f, 0.f};

  for (int pass = 0; pass < 2; ++pass) {
    const int qb = (pass == 0) ? (63 - j) : j;      // 32-row q-tile index
    const int q0 = qb * 32;
    const int qrow = q0 + w * 16;                   // wave fragment
    const int nt = (qb >> 1) + 1;                   // kv tiles (64-wide)

    bf16x8 qf0 = *reinterpret_cast<const bf16x8*>(Qp + (size_t)(qrow + c) * HDIM + g * 8);
    bf16x8 qf1 = *reinterpret_cast<const bf16x8*>(Qp + (size_t)(qrow + c) * HDIM + 32 + g * 8);

    {
      const int kv0 = (nt - 1) * 64;
      const u16* ks = KsB + kv0 * 64;
      const u16* vs = VsB + kv0;
      gl_lds16(ks,         kd0);
      gl_lds16(ks + 1024,  kd0 + 1024);
      gl_lds16(ks + 2048,  kd0 + 2048);
      gl_lds16(ks + 3072,  kd0 + 3072);
      gl_lds16(vs,          vd0);
      gl_lds16(vs + 32768,  vd0 + 1024);
      gl_lds16(vs + 65536,  vd0 + 2048);
      gl_lds16(vs + 98304,  vd0 + 3072);
    }
    __syncthreads();

    f32x4 o[4];
#pragma unroll
    for (int dg = 0; dg < 4; ++dg) o[dg] = zero4;
    float lrun = 0.f;

    for (int t = 0; t < nt; ++t) {
      const int par = t & 1;
      const u16* kb = &KB[0][0][0] + par * 4096;
      const u16* vb = &VB[0][0][0] + par * 4096;

      if (t + 1 < nt) {
        const int kvn = (nt - 2 - t) * 64;
        const u16* ks = KsB + kvn * 64;
        const u16* vs = VsB + kvn;
        u16* kd = kd0 + (par ^ 1) * 4096;
        u16* vd = vd0 + (par ^ 1) * 4096;
        gl_lds16(ks,         kd);
        gl_lds16(ks + 1024,  kd + 1024);
        gl_lds16(ks + 2048,  kd + 2048);
        gl_lds16(ks + 3072,  kd + 3072);
        gl_lds16(vs,          vd);
        gl_lds16(vs + 32768,  vd + 1024);
        gl_lds16(vs + 65536,  vd + 2048);
        gl_lds16(vs + 98304,  vd + 3072);
      }

      const int kv0 = (nt - 1 - t) * 64;

      const u16* kA = kb + koffA;
      const u16* kBp = kb + koffB;
      f32x4 s[4];
#pragma unroll
      for (int jj = 0; jj < 4; ++jj) {
        bf16x8 k0 = *reinterpret_cast<const bf16x8*>(kA + jj * 1024);
        bf16x8 k1 = *reinterpret_cast<const bf16x8*>(kBp + jj * 1024);
        f32x4 z4 = zero4;
        z4 = __builtin_amdgcn_mfma_f32_16x16x32_bf16(k0, qf0, z4, 0, 0, 0);
        z4 = __builtin_amdgcn_mfma_f32_16x16x32_bf16(k1, qf1, z4, 0, 0, 0);
        s[jj] = z4;
      }

      const int kbase = kv0 + 4 * g - (qrow + c);
      float p[16];
      if (t == 0) {
#pragma unroll
        for (int jj = 0; jj < 4; ++jj)
#pragma unroll
          for (int i = 0; i < 4; ++i) {
            int rel = kbase + 16 * jj + i;
            float sv = s[jj][i] + slope2 * (float)rel;
            if (rel > 0) sv = -3.0e38f;
            float e = __builtin_amdgcn_exp2f(sv);
            p[jj * 4 + i] = e;
            lrun += e;
          }
      } else {
        const float bb2 = slope2 * (float)kbase;
#pragma unroll
        for (int jj = 0; jj < 4; ++jj)
#pragma unroll
          for (int i = 0; i < 4; ++i) {
            float e = __builtin_amdgcn_exp2f(
                s[jj][i] + (bb2 + slope2 * (float)(16 * jj + i)));
            p[jj * 4 + i] = e;
            lrun += e;
          }
      }
      union PU { bf16x8 v; u32x4 u; };
      PU P0, P1;
#pragma unroll
      for (int k = 0; k < 4; ++k) {
        P0.u[k] = cvt_pk_bf16(p[2 * k], p[2 * k + 1]);
        P1.u[k] = cvt_pk_bf16(p[8 + 2 * k], p[8 + 2 * k + 1]);
      }

      const u16* vpA = vb + voffA;
      const u16* vpB = vb + voffB;
#pragma unroll
      for (int dg = 0; dg < 4; ++dg) {
        bf16x8 vf0 = *reinterpret_cast<const bf16x8*>(vpA + dg * 1024);
        bf16x8 vf1 = *reinterpret_cast<const bf16x8*>(vpB + dg * 1024);
        o[dg] = __builtin_amdgcn_mfma_f32_16x16x32_bf16(P0.v, vf0, o[dg], 0, 0, 0);
        o[dg] = __builtin_amdgcn_mfma_f32_16x16x32_bf16(P1.v, vf1, o[dg], 0, 0, 0);
      }

      __syncthreads();
    }

    lrun += __shfl_xor(lrun, 16, 64);
    lrun += __shfl_xor(lrun, 32, 64);
    float rl[4];
#pragma unroll
    for (int i = 0; i < 4; ++i) {
      float li = __shfl(lrun, g * 4 + i, 64);
      rl[i] = 1.0f / li;
    }
#pragma unroll
    for (int dg = 0; dg < 4; ++dg) {
#pragma unroll
      for (int i = 0; i < 4; ++i) {
        int qi = qrow + g * 4 + i;
        O[((size_t)b * T_SEQ + qi) * DMODEL + h * HDIM + dg * 16 + c] =
            f2bf(o[dg][i] * rl[i]);
      }
    }
    __syncthreads();
  }
}

// ---------------------------------------------------------------------------
// Output projection, r7 (verbatim): 128x128 tile, BK=64 dbuf 2-phase K-loop.
__global__ __launch_bounds__(256) void out_gemm(
    const u16* __restrict__ ao, const u16* __restrict__ wp,
    const float* __restrict__ bp, float* __restrict__ out)
{
  const int K = DMODEL;
  const int bm = blockIdx.y, bn = blockIdx.x;
  const int tid = threadIdx.x;
  const int w = tid >> 6, lane = tid & 63, g = lane >> 4, c = lane & 15;
  const int wm = w >> 1, wn = w & 1;

  __shared__ u16 SM[2][2][128][64];   // 64 KB

  f32x4 zero4 = {0.f, 0.f, 0.f, 0.f};
  f32x4 acc[4][4];
#pragma unroll
  for (int m = 0; m < 4; ++m)
#pragma unroll
    for (int n = 0; n < 4; ++n) acc[m][n] = zero4;

  int rr[4], cswz[4];
#pragma unroll
  for (int j = 0; j < 4; ++j) {
    int chunk = tid + 256 * j;
    rr[j] = chunk >> 3;
    cswz[j] = ((chunk & 7) ^ (rr[j] & 7)) * 8;
  }

  // prologue: stage k0=0 into buf 0
#pragma unroll
  for (int j = 0; j < 4; ++j) {
    int chunk = tid + 256 * j;
    gl_lds16(ao + (size_t)(bm * 128 + rr[j]) * K + cswz[j],
             &SM[0][0][0][0] + chunk * 8);
    gl_lds16(wp + (size_t)(bn * 128 + rr[j]) * K + cswz[j],
             &SM[0][1][0][0] + chunk * 8);
  }
  __syncthreads();

  for (int t = 0; t < 16; ++t) {
    const int buf = t & 1;
    if (t < 15) {
      const int k0 = (t + 1) * 64;
#pragma unroll
      for (int j = 0; j < 4; ++j) {
        int chunk = tid + 256 * j;
        gl_lds16(ao + (size_t)(bm * 128 + rr[j]) * K + k0 + cswz[j],
                 &SM[buf ^ 1][0][0][0] + chunk * 8);
        gl_lds16(wp + (size_t)(bn * 128 + rr[j]) * K + k0 + cswz[j],
                 &SM[buf ^ 1][1][0][0] + chunk * 8);
      }
    }
#pragma unroll
    for (int kk = 0; kk < 2; ++kk) {
      bf16x8 af[4], bfr[4];
#pragma unroll
      for (int m = 0; m < 4; ++m) {
        int row = wm * 64 + m * 16 + c;
        af[m] = *reinterpret_cast<const bf16x8*>(
            &SM[buf][0][row][(kk * 32 + g * 8) ^ ((row & 7) * 8)]);
      }
#pragma unroll
      for (int n = 0; n < 4; ++n) {
        int row = wn * 64 + n * 16 + c;
        bfr[n] = *reinterpret_cast<const bf16x8*>(
            &SM[buf][1][row][(kk * 32 + g * 8) ^ ((row & 7) * 8)]);
      }
#pragma unroll
      for (int m = 0; m < 4; ++m)
#pragma unroll
        for (int n = 0; n < 4; ++n)
          acc[m][n] = __builtin_amdgcn_mfma_f32_16x16x32_bf16(af[m], bfr[n], acc[m][n], 0, 0, 0);
    }
    __syncthreads();
  }

#pragma unroll
  for (int m = 0; m < 4; ++m) {
    int mrow_base = bm * 128 + wm * 64 + m * 16 + g * 4;
#pragma unroll
    for (int n = 0; n < 4; ++n) {
      int n_idx = bn * 128 + wn * 64 + n * 16 + c;
      float bv_ = bp[n_idx];
#pragma unroll
      for (int i = 0; i < 4; ++i) {
        int mrow = mrow_base + i;
        out[(size_t)mrow * DMODEL + n_idx] = acc[m][n][i] + bv_;
      }
    }
  }
}

// ---------------------------------------------------------------------------
extern "C" void kernel_launch(void* const* d_in, const int* in_sizes, int n_in,
                              void* d_out, int out_size, void* d_ws, size_t ws_size,
                              hipStream_t stream) {
  const float* x  = (const float*)d_in[0];
  const float* Wq = (const float*)d_in[1];
  const float* bq = (const float*)d_in[2];
  const float* Wk = (const float*)d_in[3];
  const float* bk = (const float*)d_in[4];
  const float* Wv = (const float*)d_in[5];
  const float* bv = (const float*)d_in[6];
  const float* Wp = (const float*)d_in[7];
  const float* bp = (const float*)d_in[8];
  float* out = (float*)d_out;

  u16* ws    = (u16*)d_ws;
  u16* xb    = ws;                       // 4,194,304  (x as bf16)
  u16* wqb   = xb   + 4194304;           // 4 x 1,048,576 contiguous
  u16* wkb   = wqb  + 1048576;
  u16* wvb   = wkb  + 1048576;
  u16* wpb   = wvb  + 1048576;
  u16* q_ws  = wpb  + 1048576;           // [B,NH,T,hd] (scaled by rs*log2e)
  u16* k_ws  = q_ws + 4194304;           // [B,NH,T,hd] (scaled by rs)
  u16* vt_ws = k_ws + 4194304;           // [B,NH,hd,T] PERMUTED per 64-t block
  u16* ao    = vt_ws + 4194304;          // [B,T,D] attention output

  cvt_all<<<dim3(1024, 8), 256, 0, stream>>>(x, Wq, Wk, Wv, Wp, ws);

  qkv_gemm<<<dim3(DMODEL / 128, MROWS / 128, 3), 256, 0, stream>>>(
      xb, wqb, wkb, wvb, bq, bk, bv, q_ws, k_ws, vt_ws);

  attn_fused<<<1024, 128, 0, stream>>>(q_ws, k_ws, vt_ws, ao);

  out_gemm<<<dim3(DMODEL / 128, MROWS / 128), 256, 0, stream>>>(ao, wpb, bp, out);
}